// Round 1
// baseline (1736.753 us; speedup 1.0000x reference)
//
#include <hip/hip_runtime.h>
#include <hip/hip_bf16.h>
#include <math.h>

typedef _Float16 f16;
typedef _Float16 half8 __attribute__((ext_vector_type(8)));
typedef float f32x4 __attribute__((ext_vector_type(4)));

#define B_ 16
#define S_ 4096
#define D_ 1024
#define F_ 1024
#define TOK (B_*S_)
#define TB 64
#define FB 128
#define NFB (F_/FB)   // 8
#define BK 32

// ---------------- kernel 0a: convert x fp32 -> fp16 ----------------
__global__ void cvt_x(const float* __restrict__ x, f16* __restrict__ xh) {
    size_t i = ((size_t)blockIdx.x * 256 + threadIdx.x) * 8;
    float4 a = *(const float4*)(x + i);
    float4 b = *(const float4*)(x + i + 4);
    half8 h = {(f16)a.x,(f16)a.y,(f16)a.z,(f16)a.w,
               (f16)b.x,(f16)b.y,(f16)b.z,(f16)b.w};
    *(half8*)(xh + i) = h;
}

// ------------- kernel 0b: transpose+convert Wk,Wq -> wt[2][F][D] -------------
__global__ void cvt_w(const float* __restrict__ Wk, const float* __restrict__ Wq,
                      f16* __restrict__ wt) {
    __shared__ float tile[32][33];
    const float* W = (blockIdx.z == 0) ? Wk : Wq;
    f16* outp = wt + (size_t)blockIdx.z * D_ * F_;
    int x0 = blockIdx.x * 32, y0 = blockIdx.y * 32;
    int tx = threadIdx.x, ty = threadIdx.y;
#pragma unroll
    for (int i = 0; i < 4; i++)
        tile[ty + i*8][tx] = W[(size_t)(y0 + ty + i*8) * F_ + x0 + tx];
    __syncthreads();
#pragma unroll
    for (int i = 0; i < 4; i++)
        outp[(size_t)(x0 + ty + i*8) * D_ + y0 + tx] = (f16)tile[tx][ty + i*8];
}

// ------------- kernel 1: fused Q/K GEMM + tanh + diag-dot partials -------------
// grid (TOK/TB, NFB), block 256.  part[fb][tok] = sum_{f in fb} tanh(xWq)*tanh(xWk)
__launch_bounds__(256)
__global__ void score_gemm(const f16* __restrict__ xh, const f16* __restrict__ wt,
                           float* __restrict__ part) {
    __shared__ f16 Xs[TB][40];        // +8 pad, keeps rows 16B-aligned (80B stride)
    __shared__ f16 Ws[2][FB][40];
    __shared__ float sred[2][TB];

    const int tok0 = blockIdx.x * TB;
    const int f0   = blockIdx.y * FB;
    const int t    = threadIdx.x;
    const int w    = t >> 6, lane = t & 63;
    const int wRow = (w >> 1) * 32;   // token offset of wave
    const int wCol = (w & 1) * 64;    // f offset of wave

    f32x4 accQ[2][4] = {};
    f32x4 accK[2][4] = {};

    for (int kk = 0; kk < D_ / BK; ++kk) {
        const int k0 = kk * BK;
        __syncthreads();
        // stage X tile [64 tokens][32 k]
        {
            int token = t >> 2, p4 = t & 3;
            half8 v = *(const half8*)(xh + (size_t)(tok0 + token) * D_ + k0 + p4 * 8);
            *(half8*)&Xs[token][p4 * 8] = v;
        }
        // stage W tiles [128 f][32 k] for both matrices (wt is [f][d])
#pragma unroll
        for (int m = 0; m < 2; ++m) {
            int ff = t >> 1, pp = t & 1;
            const f16* src = wt + (size_t)m * D_ * F_ + (size_t)(f0 + ff) * D_ + k0 + pp * 16;
            half8 v0 = *(const half8*)src;
            half8 v1 = *(const half8*)(src + 8);
            *(half8*)&Ws[m][ff][pp * 16]     = v0;
            *(half8*)&Ws[m][ff][pp * 16 + 8] = v1;
        }
        __syncthreads();

        half8 aF[2];
#pragma unroll
        for (int m = 0; m < 2; ++m)
            aF[m] = *(const half8*)&Xs[wRow + m * 16 + (lane & 15)][(lane >> 4) * 8];
#pragma unroll
        for (int n = 0; n < 4; ++n) {
            half8 bK = *(const half8*)&Ws[0][wCol + n * 16 + (lane & 15)][(lane >> 4) * 8];
            half8 bQ = *(const half8*)&Ws[1][wCol + n * 16 + (lane & 15)][(lane >> 4) * 8];
#pragma unroll
            for (int m = 0; m < 2; ++m) {
                accK[m][n] = __builtin_amdgcn_mfma_f32_16x16x32_f16(aF[m], bK, accK[m][n], 0, 0, 0);
                accQ[m][n] = __builtin_amdgcn_mfma_f32_16x16x32_f16(aF[m], bQ, accQ[m][n], 0, 0, 0);
            }
        }
    }

    // epilogue: tanh, elementwise product, reduce over f within wave, combine waves
#pragma unroll
    for (int m = 0; m < 2; ++m) {
        float sum[4] = {0.f, 0.f, 0.f, 0.f};
#pragma unroll
        for (int n = 0; n < 4; ++n)
#pragma unroll
            for (int j = 0; j < 4; ++j)
                sum[j] += tanhf(accQ[m][n][j]) * tanhf(accK[m][n][j]);
#pragma unroll
        for (int j = 0; j < 4; ++j) {
            sum[j] += __shfl_xor(sum[j], 1);
            sum[j] += __shfl_xor(sum[j], 2);
            sum[j] += __shfl_xor(sum[j], 4);
            sum[j] += __shfl_xor(sum[j], 8);
        }
        if ((lane & 15) == 0) {
            int g = lane >> 4;
#pragma unroll
            for (int j = 0; j < 4; ++j)
                sred[w & 1][wRow + m * 16 + g * 4 + j] = sum[j];
        }
    }
    __syncthreads();
    if (t < TB)
        part[(size_t)blockIdx.y * TOK + tok0 + t] = sred[0][t] + sred[1][t];
}

// ------------- kernel 2: per-batch softmax over S -------------
__global__ void softmax_k(const float* __restrict__ part, float* __restrict__ out) {
    __shared__ float sc[S_];
    __shared__ float red[256];
    const int b = blockIdx.x, t = threadIdx.x;
    float lmax = -1e30f;
    for (int i = t; i < S_; i += 256) {
        float s = 0.f;
#pragma unroll
        for (int fb = 0; fb < NFB; ++fb) s += part[(size_t)fb * TOK + b * S_ + i];
        sc[i] = s;
        lmax = fmaxf(lmax, s);
    }
    red[t] = lmax; __syncthreads();
    for (int o = 128; o > 0; o >>= 1) { if (t < o) red[t] = fmaxf(red[t], red[t + o]); __syncthreads(); }
    const float mx = red[0]; __syncthreads();
    float lsum = 0.f;
    for (int i = t; i < S_; i += 256) { float e = expf(sc[i] - mx); sc[i] = e; lsum += e; }
    red[t] = lsum; __syncthreads();
    for (int o = 128; o > 0; o >>= 1) { if (t < o) red[t] += red[t + o]; __syncthreads(); }
    const float inv = 1.0f / red[0];
    for (int i = t; i < S_; i += 256)
        out[(size_t)B_ * F_ + (size_t)b * S_ + i] = sc[i] * inv;
}

// ------------- kernel 3: sparse value pass (exact fp32) -------------
// weighted[b][f] = sum_{s: p>eps} p_s * tanh(x_s . Wv[:,f])
__launch_bounds__(256)
__global__ void value_k(const float* __restrict__ x, const float* __restrict__ Wv,
                        float* __restrict__ out) {
    __shared__ float pr[S_];
    __shared__ float xs[D_];
    const int b = blockIdx.y;
    const int f = blockIdx.x * 256 + threadIdx.x;
    const int t = threadIdx.x;
    for (int i = t; i < S_; i += 256) pr[i] = out[(size_t)B_ * F_ + (size_t)b * S_ + i];
    __syncthreads();
    float acc = 0.f;
    for (int s = 0; s < S_; ++s) {
        float p = pr[s];
        if (p > 1e-7f) {               // uniform branch (p broadcast from LDS)
            __syncthreads();
            for (int i = t; i < D_; i += 256) xs[i] = x[((size_t)b * S_ + s) * D_ + i];
            __syncthreads();
            float a = 0.f;
#pragma unroll 8
            for (int d = 0; d < D_; ++d) a += xs[d] * Wv[(size_t)d * F_ + f];
            acc += p * tanhf(a);
        }
    }
    out[(size_t)b * F_ + f] = acc;
}

extern "C" void kernel_launch(void* const* d_in, const int* in_sizes, int n_in,
                              void* d_out, int out_size, void* d_ws, size_t ws_size,
                              hipStream_t stream) {
    const float* x  = (const float*)d_in[0];
    const float* Wk = (const float*)d_in[1];
    const float* Wq = (const float*)d_in[2];
    const float* Wv = (const float*)d_in[3];
    float* out = (float*)d_out;
    char* ws = (char*)d_ws;

    f16*   xh   = (f16*)ws;                                              // 128 MB
    f16*   wt   = (f16*)(ws + (size_t)TOK * D_ * 2);                     // 4 MB
    float* part = (float*)(ws + (size_t)TOK * D_ * 2 + 2 * (size_t)D_ * F_ * 2); // 2 MB

    cvt_x<<<TOK * D_ / 8 / 256, 256, 0, stream>>>(x, xh);
    cvt_w<<<dim3(32, 32, 2), dim3(32, 8), 0, stream>>>(Wk, Wq, wt);
    score_gemm<<<dim3(TOK / TB, NFB), 256, 0, stream>>>(xh, wt, part);
    softmax_k<<<B_, 256, 0, stream>>>(part, out);
    value_k<<<dim3(F_ / 256, B_), 256, 0, stream>>>(x, Wv, out);
}

// Round 2
// 1099.300 us; speedup vs baseline: 1.5799x; 1.5799x over previous
//
#include <hip/hip_runtime.h>
#include <hip/hip_bf16.h>
#include <math.h>

typedef _Float16 f16;
typedef _Float16 half8 __attribute__((ext_vector_type(8)));
typedef float f32x4 __attribute__((ext_vector_type(4)));

#define B_ 16
#define S_ 4096
#define D_ 1024
#define F_ 1024
#define TOK (B_*S_)
#define TB 64
#define FB 128
#define NFB (F_/FB)   // 8
#define BK 32
#define NS 16
#define CS (S_/NS)    // 256

// ---------------- kernel 0a: convert x fp32 -> fp16 ----------------
__global__ void cvt_x(const float* __restrict__ x, f16* __restrict__ xh) {
    size_t i = ((size_t)blockIdx.x * 256 + threadIdx.x) * 8;
    float4 a = *(const float4*)(x + i);
    float4 b = *(const float4*)(x + i + 4);
    half8 h = {(f16)a.x,(f16)a.y,(f16)a.z,(f16)a.w,
               (f16)b.x,(f16)b.y,(f16)b.z,(f16)b.w};
    *(half8*)(xh + i) = h;
}

// ------------- kernel 0b: transpose+convert Wk,Wq -> wt[2][F][D] -------------
__global__ void cvt_w(const float* __restrict__ Wk, const float* __restrict__ Wq,
                      f16* __restrict__ wt) {
    __shared__ float tile[32][33];
    const float* W = (blockIdx.z == 0) ? Wk : Wq;
    f16* outp = wt + (size_t)blockIdx.z * D_ * F_;
    int x0 = blockIdx.x * 32, y0 = blockIdx.y * 32;
    int tx = threadIdx.x, ty = threadIdx.y;
#pragma unroll
    for (int i = 0; i < 4; i++)
        tile[ty + i*8][tx] = W[(size_t)(y0 + ty + i*8) * F_ + x0 + tx];
    __syncthreads();
#pragma unroll
    for (int i = 0; i < 4; i++)
        outp[(size_t)(x0 + ty + i*8) * D_ + y0 + tx] = (f16)tile[tx][ty + i*8];
}

// ------------- kernel 1: fused Q/K GEMM + tanh + diag-dot partials -------------
// grid (TOK/TB, NFB), block 256.  part[fb][tok] = sum_{f in fb} tanh(xWq)*tanh(xWk)
__launch_bounds__(256)
__global__ void score_gemm(const f16* __restrict__ xh, const f16* __restrict__ wt,
                           float* __restrict__ part) {
    __shared__ f16 Xs[TB][40];        // +8 pad, keeps rows 16B-aligned (80B stride)
    __shared__ f16 Ws[2][FB][40];
    __shared__ float sred[2][TB];

    const int tok0 = blockIdx.x * TB;
    const int f0   = blockIdx.y * FB;
    const int t    = threadIdx.x;
    const int w    = t >> 6, lane = t & 63;
    const int wRow = (w >> 1) * 32;   // token offset of wave
    const int wCol = (w & 1) * 64;    // f offset of wave

    f32x4 accQ[2][4] = {};
    f32x4 accK[2][4] = {};

    for (int kk = 0; kk < D_ / BK; ++kk) {
        const int k0 = kk * BK;
        __syncthreads();
        // stage X tile [64 tokens][32 k]
        {
            int token = t >> 2, p4 = t & 3;
            half8 v = *(const half8*)(xh + (size_t)(tok0 + token) * D_ + k0 + p4 * 8);
            *(half8*)&Xs[token][p4 * 8] = v;
        }
        // stage W tiles [128 f][32 k] for both matrices (wt is [f][d])
#pragma unroll
        for (int m = 0; m < 2; ++m) {
            int ff = t >> 1, pp = t & 1;
            const f16* src = wt + (size_t)m * D_ * F_ + (size_t)(f0 + ff) * D_ + k0 + pp * 16;
            half8 v0 = *(const half8*)src;
            half8 v1 = *(const half8*)(src + 8);
            *(half8*)&Ws[m][ff][pp * 16]     = v0;
            *(half8*)&Ws[m][ff][pp * 16 + 8] = v1;
        }
        __syncthreads();

        half8 aF[2];
#pragma unroll
        for (int m = 0; m < 2; ++m)
            aF[m] = *(const half8*)&Xs[wRow + m * 16 + (lane & 15)][(lane >> 4) * 8];
#pragma unroll
        for (int n = 0; n < 4; ++n) {
            half8 bK = *(const half8*)&Ws[0][wCol + n * 16 + (lane & 15)][(lane >> 4) * 8];
            half8 bQ = *(const half8*)&Ws[1][wCol + n * 16 + (lane & 15)][(lane >> 4) * 8];
#pragma unroll
            for (int m = 0; m < 2; ++m) {
                accK[m][n] = __builtin_amdgcn_mfma_f32_16x16x32_f16(aF[m], bK, accK[m][n], 0, 0, 0);
                accQ[m][n] = __builtin_amdgcn_mfma_f32_16x16x32_f16(aF[m], bQ, accQ[m][n], 0, 0, 0);
            }
        }
    }

    // epilogue: tanh, elementwise product, reduce over f within wave, combine waves
#pragma unroll
    for (int m = 0; m < 2; ++m) {
        float sum[4] = {0.f, 0.f, 0.f, 0.f};
#pragma unroll
        for (int n = 0; n < 4; ++n)
#pragma unroll
            for (int j = 0; j < 4; ++j)
                sum[j] += tanhf(accQ[m][n][j]) * tanhf(accK[m][n][j]);
#pragma unroll
        for (int j = 0; j < 4; ++j) {
            sum[j] += __shfl_xor(sum[j], 1);
            sum[j] += __shfl_xor(sum[j], 2);
            sum[j] += __shfl_xor(sum[j], 4);
            sum[j] += __shfl_xor(sum[j], 8);
        }
        if ((lane & 15) == 0) {
            int g = lane >> 4;
#pragma unroll
            for (int j = 0; j < 4; ++j)
                sred[w & 1][wRow + m * 16 + g * 4 + j] = sum[j];
        }
    }
    __syncthreads();
    if (t < TB)
        part[(size_t)blockIdx.y * TOK + tok0 + t] = sred[0][t] + sred[1][t];
}

// ------------- kernel 2: per-batch softmax over S -------------
__global__ void softmax_k(const float* __restrict__ part, float* __restrict__ out) {
    __shared__ float sc[S_];
    __shared__ float red[256];
    const int b = blockIdx.x, t = threadIdx.x;
    float lmax = -1e30f;
    for (int i = t; i < S_; i += 256) {
        float s = 0.f;
#pragma unroll
        for (int fb = 0; fb < NFB; ++fb) s += part[(size_t)fb * TOK + b * S_ + i];
        sc[i] = s;
        lmax = fmaxf(lmax, s);
    }
    red[t] = lmax; __syncthreads();
    for (int o = 128; o > 0; o >>= 1) { if (t < o) red[t] = fmaxf(red[t], red[t + o]); __syncthreads(); }
    const float mx = red[0]; __syncthreads();
    float lsum = 0.f;
    for (int i = t; i < S_; i += 256) { float e = expf(sc[i] - mx); sc[i] = e; lsum += e; }
    red[t] = lsum; __syncthreads();
    for (int o = 128; o > 0; o >>= 1) { if (t < o) red[t] += red[t + o]; __syncthreads(); }
    const float inv = 1.0f / red[0];
    for (int i = t; i < S_; i += 256)
        out[(size_t)B_ * F_ + (size_t)b * S_ + i] = sc[i] * inv;
}

// ------------- kernel 3: sparse value pass, S-chunked partials -------------
// vpart[c][b][f] = sum_{s in chunk c, p>eps} p_s * tanh(x_s . Wv[:,f])
__launch_bounds__(256)
__global__ void value_k2(const float* __restrict__ x, const float* __restrict__ Wv,
                         const float* __restrict__ p_in, float* __restrict__ vpart) {
    __shared__ float xs[8][D_];       // 32 KB: up to 8 staged token rows
    __shared__ float pr[CS];
    __shared__ int   idxs[CS];
    __shared__ float ps[CS];
    __shared__ int   cnt_s;
    const int b = blockIdx.y, c = blockIdx.z;
    const int f = blockIdx.x * 256 + threadIdx.x;
    const int t = threadIdx.x;
    const int s0 = c * CS;

    for (int i = t; i < CS; i += 256) pr[i] = p_in[(size_t)b * S_ + s0 + i];
    __syncthreads();
    if (t == 0) {                      // ordered deterministic compaction
        int cn = 0;
        for (int i = 0; i < CS; ++i)
            if (pr[i] > 1e-7f) { idxs[cn] = s0 + i; ps[cn] = pr[i]; ++cn; }
        cnt_s = cn;
    }
    __syncthreads();
    const int cnt = cnt_s;

    float acc = 0.f;
    for (int g = 0; g < cnt; g += 8) {
        const int ng = min(8, cnt - g);
        __syncthreads();               // protect xs reuse across groups
#pragma unroll
        for (int t8 = 0; t8 < 8; ++t8)
            if (t8 < ng) {
                const float4* src = (const float4*)(x + ((size_t)b * S_ + idxs[g + t8]) * D_);
                ((float4*)xs[t8])[t] = src[t];     // 256 thr x 16B = full 4KB row
            }
        __syncthreads();
        float a[8] = {0.f,0.f,0.f,0.f,0.f,0.f,0.f,0.f};
#pragma unroll 4
        for (int d = 0; d < D_; ++d) {
            float wv = Wv[(size_t)d * F_ + f];
#pragma unroll
            for (int t8 = 0; t8 < 8; ++t8)
                if (t8 < ng) a[t8] += xs[t8][d] * wv;
        }
#pragma unroll
        for (int t8 = 0; t8 < 8; ++t8)
            if (t8 < ng) acc += ps[g + t8] * tanhf(a[t8]);
    }
    vpart[((size_t)c * B_ + b) * F_ + f] = acc;
}

// ------------- kernel 4: reduce chunk partials -------------
__global__ void value_red(const float* __restrict__ vpart, float* __restrict__ out) {
    int i = blockIdx.x * 256 + threadIdx.x;   // [0, B_*F_)
    float s = 0.f;
#pragma unroll
    for (int c = 0; c < NS; ++c) s += vpart[(size_t)c * B_ * F_ + i];
    out[i] = s;
}

extern "C" void kernel_launch(void* const* d_in, const int* in_sizes, int n_in,
                              void* d_out, int out_size, void* d_ws, size_t ws_size,
                              hipStream_t stream) {
    const float* x  = (const float*)d_in[0];
    const float* Wk = (const float*)d_in[1];
    const float* Wq = (const float*)d_in[2];
    const float* Wv = (const float*)d_in[3];
    float* out = (float*)d_out;
    char* ws = (char*)d_ws;

    f16*   xh   = (f16*)ws;                                              // 128 MB
    f16*   wt   = (f16*)(ws + (size_t)TOK * D_ * 2);                     // 4 MB
    float* part = (float*)(ws + (size_t)TOK * D_ * 2 + 2 * (size_t)D_ * F_ * 2); // 2 MB

    cvt_x<<<TOK * D_ / 8 / 256, 256, 0, stream>>>(x, xh);
    cvt_w<<<dim3(32, 32, 2), dim3(32, 8), 0, stream>>>(Wk, Wq, wt);
    score_gemm<<<dim3(TOK / TB, NFB), 256, 0, stream>>>(xh, wt, part);
    softmax_k<<<B_, 256, 0, stream>>>(part, out);
    // part buffer is free after softmax_k -> reuse as value partials (1 MB <= 2 MB)
    float* vpart = part;
    const float* p_in = out + (size_t)B_ * F_;
    value_k2<<<dim3(F_ / 256, B_, NS), 256, 0, stream>>>(x, Wv, p_in, vpart);
    value_red<<<B_ * F_ / 256, 256, 0, stream>>>(vpart, out);
}

// Round 3
// 914.725 us; speedup vs baseline: 1.8987x; 1.2018x over previous
//
#include <hip/hip_runtime.h>
#include <hip/hip_bf16.h>
#include <math.h>
#include <stdint.h>

typedef _Float16 f16;
typedef _Float16 half8 __attribute__((ext_vector_type(8)));
typedef float f32x4 __attribute__((ext_vector_type(4)));

#define B_ 16
#define S_ 4096
#define D_ 1024
#define F_ 1024
#define TOK (B_*S_)
#define TB 128
#define FB 128
#define NFB (F_/FB)   // 8
#define BK 32
#define NS 16
#define CS (S_/NS)    // 256

// async global->LDS, 16B per lane; lds dest must be wave-uniform base (+lane*16 by HW)
__device__ __forceinline__ void gload_lds16(const void* g, void* l) {
    __builtin_amdgcn_global_load_lds(
        (__attribute__((address_space(1))) const unsigned int*)(unsigned long long)(uintptr_t)g,
        (__attribute__((address_space(3))) unsigned int*)(unsigned int)(uintptr_t)l,
        16, 0, 0);
}

// ---------------- kernel 0a: convert x fp32 -> fp16 ----------------
__global__ void cvt_x(const float* __restrict__ x, f16* __restrict__ xh) {
    size_t i = ((size_t)blockIdx.x * 256 + threadIdx.x) * 8;
    float4 a = *(const float4*)(x + i);
    float4 b = *(const float4*)(x + i + 4);
    half8 h = {(f16)a.x,(f16)a.y,(f16)a.z,(f16)a.w,
               (f16)b.x,(f16)b.y,(f16)b.z,(f16)b.w};
    *(half8*)(xh + i) = h;
}

// ------------- kernel 0b: transpose+convert Wk,Wq -> wt[2][F][D] -------------
__global__ void cvt_w(const float* __restrict__ Wk, const float* __restrict__ Wq,
                      f16* __restrict__ wt) {
    __shared__ float tile[32][33];
    const float* W = (blockIdx.z == 0) ? Wk : Wq;
    f16* outp = wt + (size_t)blockIdx.z * D_ * F_;
    int x0 = blockIdx.x * 32, y0 = blockIdx.y * 32;
    int tx = threadIdx.x, ty = threadIdx.y;
#pragma unroll
    for (int i = 0; i < 4; i++)
        tile[ty + i*8][tx] = W[(size_t)(y0 + ty + i*8) * F_ + x0 + tx];
    __syncthreads();
#pragma unroll
    for (int i = 0; i < 4; i++)
        outp[(size_t)(x0 + ty + i*8) * D_ + y0 + tx] = (f16)tile[tx][ty + i*8];
}

// ------------- kernel 1: fused Q/K GEMM + tanh + diag-dot partials -------------
// m97 structure: 128x128 tile, 4 waves (2x2), each wave 64 tok x 64 f for BOTH
// matrices; BK=32; linear LDS staged via global_load_lds width=16.
__launch_bounds__(256, 2)
__global__ void score_gemm(const f16* __restrict__ xh, const f16* __restrict__ wt,
                           float* __restrict__ part) {
    __shared__ __align__(16) f16 Xs[TB][32];    // 8 KB, rows 64B, NO pad (gload_lds linear)
    __shared__ __align__(16) f16 WsK[FB][32];   // 8 KB
    __shared__ __align__(16) f16 WsQ[FB][32];   // 8 KB
    __shared__ float sred[2][TB];

    const int tok0 = blockIdx.x * TB;
    const int f0   = blockIdx.y * FB;
    const int t    = threadIdx.x;
    const int lane = t & 63;
    const int w    = t >> 6;
    const int wr   = (w >> 1) * 64;   // token offset of wave's sub-tile
    const int wc   = (w & 1) * 64;    // f offset of wave's sub-tile

    // staging decomposition: chunk c in [0,512): row=c>>2, 16B-chunk=(c&3)
    const int c0 = t, c1 = t + 256;
    const int r0 = c0 >> 2, q0 = (c0 & 3) * 8;   // q in f16 elements
    const int r1 = c1 >> 2, q1 = (c1 & 3) * 8;
    char* ldsX = (char*)Xs  + (size_t)(t - lane) * 16;  // wave-uniform base
    char* ldsK = (char*)WsK + (size_t)(t - lane) * 16;
    char* ldsQ = (char*)WsQ + (size_t)(t - lane) * 16;

    const f16* wK = wt + (size_t)f0 * D_;
    const f16* wQ = wt + (size_t)D_ * F_ + (size_t)f0 * D_;

    f32x4 accQ[4][4] = {};
    f32x4 accK[4][4] = {};

    for (int k0 = 0; k0 < D_; k0 += BK) {
        __syncthreads();   // previous compute done before overwrite
        gload_lds16(xh + (size_t)(tok0 + r0) * D_ + k0 + q0, ldsX);
        gload_lds16(xh + (size_t)(tok0 + r1) * D_ + k0 + q1, ldsX + 4096);
        gload_lds16(wK + (size_t)r0 * D_ + k0 + q0, ldsK);
        gload_lds16(wK + (size_t)r1 * D_ + k0 + q1, ldsK + 4096);
        gload_lds16(wQ + (size_t)r0 * D_ + k0 + q0, ldsQ);
        gload_lds16(wQ + (size_t)r1 * D_ + k0 + q1, ldsQ + 4096);
        __syncthreads();   // compiler drains vmcnt before barrier

        half8 aF[4], bK[4], bQ[4];
#pragma unroll
        for (int m = 0; m < 4; ++m)
            aF[m] = *(const half8*)&Xs[wr + m * 16 + (lane & 15)][(lane >> 4) * 8];
#pragma unroll
        for (int n = 0; n < 4; ++n) {
            bK[n] = *(const half8*)&WsK[wc + n * 16 + (lane & 15)][(lane >> 4) * 8];
            bQ[n] = *(const half8*)&WsQ[wc + n * 16 + (lane & 15)][(lane >> 4) * 8];
        }
#pragma unroll
        for (int n = 0; n < 4; ++n)
#pragma unroll
            for (int m = 0; m < 4; ++m) {
                accK[m][n] = __builtin_amdgcn_mfma_f32_16x16x32_f16(aF[m], bK[n], accK[m][n], 0, 0, 0);
                accQ[m][n] = __builtin_amdgcn_mfma_f32_16x16x32_f16(aF[m], bQ[n], accQ[m][n], 0, 0, 0);
            }
    }

    // epilogue: tanh, product, reduce over f (lane&15 cols + n), combine wave cols
#pragma unroll
    for (int m = 0; m < 4; ++m) {
        float s[4] = {0.f, 0.f, 0.f, 0.f};
#pragma unroll
        for (int n = 0; n < 4; ++n)
#pragma unroll
            for (int j = 0; j < 4; ++j)
                s[j] += tanhf(accQ[m][n][j]) * tanhf(accK[m][n][j]);
#pragma unroll
        for (int j = 0; j < 4; ++j) {
            s[j] += __shfl_xor(s[j], 1);
            s[j] += __shfl_xor(s[j], 2);
            s[j] += __shfl_xor(s[j], 4);
            s[j] += __shfl_xor(s[j], 8);
        }
        if ((lane & 15) == 0) {
            int g = lane >> 4;
#pragma unroll
            for (int j = 0; j < 4; ++j)
                sred[w & 1][wr + m * 16 + g * 4 + j] = s[j];
        }
    }
    __syncthreads();
    if (t < TB)
        part[(size_t)blockIdx.y * TOK + tok0 + t] = sred[0][t] + sred[1][t];
}

// ------------- kernel 2: per-batch softmax over S -------------
__global__ void softmax_k(const float* __restrict__ part, float* __restrict__ out) {
    __shared__ float sc[S_];
    __shared__ float red[256];
    const int b = blockIdx.x, t = threadIdx.x;
    float lmax = -1e30f;
    for (int i = t; i < S_; i += 256) {
        float s = 0.f;
#pragma unroll
        for (int fb = 0; fb < NFB; ++fb) s += part[(size_t)fb * TOK + b * S_ + i];
        sc[i] = s;
        lmax = fmaxf(lmax, s);
    }
    red[t] = lmax; __syncthreads();
    for (int o = 128; o > 0; o >>= 1) { if (t < o) red[t] = fmaxf(red[t], red[t + o]); __syncthreads(); }
    const float mx = red[0]; __syncthreads();
    float lsum = 0.f;
    for (int i = t; i < S_; i += 256) { float e = expf(sc[i] - mx); sc[i] = e; lsum += e; }
    red[t] = lsum; __syncthreads();
    for (int o = 128; o > 0; o >>= 1) { if (t < o) red[t] += red[t + o]; __syncthreads(); }
    const float inv = 1.0f / red[0];
    for (int i = t; i < S_; i += 256)
        out[(size_t)B_ * F_ + (size_t)b * S_ + i] = sc[i] * inv;
}

// ------------- kernel 3: sparse value pass, S-chunked partials -------------
__launch_bounds__(256)
__global__ void value_k2(const float* __restrict__ x, const float* __restrict__ Wv,
                         const float* __restrict__ p_in, float* __restrict__ vpart) {
    __shared__ float xs[8][D_];
    __shared__ float pr[CS];
    __shared__ int   idxs[CS];
    __shared__ float ps[CS];
    __shared__ int   cnt_s;
    const int b = blockIdx.y, c = blockIdx.z;
    const int f = blockIdx.x * 256 + threadIdx.x;
    const int t = threadIdx.x;
    const int s0 = c * CS;

    for (int i = t; i < CS; i += 256) pr[i] = p_in[(size_t)b * S_ + s0 + i];
    __syncthreads();
    if (t == 0) {
        int cn = 0;
        for (int i = 0; i < CS; ++i)
            if (pr[i] > 1e-7f) { idxs[cn] = s0 + i; ps[cn] = pr[i]; ++cn; }
        cnt_s = cn;
    }
    __syncthreads();
    const int cnt = cnt_s;

    float acc = 0.f;
    for (int g = 0; g < cnt; g += 8) {
        const int ng = min(8, cnt - g);
        __syncthreads();
#pragma unroll
        for (int t8 = 0; t8 < 8; ++t8)
            if (t8 < ng) {
                const float4* src = (const float4*)(x + ((size_t)b * S_ + idxs[g + t8]) * D_);
                ((float4*)xs[t8])[t] = src[t];
            }
        __syncthreads();
        float a[8] = {0.f,0.f,0.f,0.f,0.f,0.f,0.f,0.f};
#pragma unroll 4
        for (int d = 0; d < D_; ++d) {
            float wv = Wv[(size_t)d * F_ + f];
#pragma unroll
            for (int t8 = 0; t8 < 8; ++t8)
                if (t8 < ng) a[t8] += xs[t8][d] * wv;
        }
#pragma unroll
        for (int t8 = 0; t8 < 8; ++t8)
            if (t8 < ng) acc += ps[g + t8] * tanhf(a[t8]);
    }
    vpart[((size_t)c * B_ + b) * F_ + f] = acc;
}

// ------------- kernel 4: reduce chunk partials -------------
__global__ void value_red(const float* __restrict__ vpart, float* __restrict__ out) {
    int i = blockIdx.x * 256 + threadIdx.x;
    float s = 0.f;
#pragma unroll
    for (int c = 0; c < NS; ++c) s += vpart[(size_t)c * B_ * F_ + i];
    out[i] = s;
}

extern "C" void kernel_launch(void* const* d_in, const int* in_sizes, int n_in,
                              void* d_out, int out_size, void* d_ws, size_t ws_size,
                              hipStream_t stream) {
    const float* x  = (const float*)d_in[0];
    const float* Wk = (const float*)d_in[1];
    const float* Wq = (const float*)d_in[2];
    const float* Wv = (const float*)d_in[3];
    float* out = (float*)d_out;
    char* ws = (char*)d_ws;

    f16*   xh   = (f16*)ws;                                              // 128 MB
    f16*   wt   = (f16*)(ws + (size_t)TOK * D_ * 2);                     // 4 MB
    float* part = (float*)(ws + (size_t)TOK * D_ * 2 + 2 * (size_t)D_ * F_ * 2); // 2 MB

    cvt_x<<<TOK * D_ / 8 / 256, 256, 0, stream>>>(x, xh);
    cvt_w<<<dim3(32, 32, 2), dim3(32, 8), 0, stream>>>(Wk, Wq, wt);
    score_gemm<<<dim3(TOK / TB, NFB), 256, 0, stream>>>(xh, wt, part);
    softmax_k<<<B_, 256, 0, stream>>>(part, out);
    float* vpart = part;
    const float* p_in = out + (size_t)B_ * F_;
    value_k2<<<dim3(F_ / 256, B_, NS), 256, 0, stream>>>(x, Wv, p_in, vpart);
    value_red<<<B_ * F_ / 256, 256, 0, stream>>>(vpart, out);
}

// Round 4
// 661.929 us; speedup vs baseline: 2.6238x; 1.3819x over previous
//
#include <hip/hip_runtime.h>
#include <hip/hip_bf16.h>
#include <math.h>
#include <stdint.h>

typedef _Float16 f16;
typedef _Float16 half8 __attribute__((ext_vector_type(8)));
typedef float f32x4 __attribute__((ext_vector_type(4)));

#define B_ 16
#define S_ 4096
#define D_ 1024
#define F_ 1024
#define TOK (B_*S_)
#define TB 128
#define FB 128
#define NFB (F_/FB)   // 8
#define BK 32
#define NS 16
#define CS (S_/NS)    // 256

// async global->LDS, 16B per lane; lds dest must be wave-uniform base (+lane*16 by HW)
__device__ __forceinline__ void gload_lds16(const void* g, void* l) {
    __builtin_amdgcn_global_load_lds(
        (__attribute__((address_space(1))) const unsigned int*)(unsigned long long)(uintptr_t)g,
        (__attribute__((address_space(3))) unsigned int*)(unsigned int)(uintptr_t)l,
        16, 0, 0);
}

__device__ __forceinline__ void fma4(float4& a, float s, const float4& wv) {
    a.x += s * wv.x; a.y += s * wv.y; a.z += s * wv.z; a.w += s * wv.w;
}
__device__ __forceinline__ void wtanh4(float4& acc, float pw, const float4& a) {
    acc.x += pw * tanhf(a.x); acc.y += pw * tanhf(a.y);
    acc.z += pw * tanhf(a.z); acc.w += pw * tanhf(a.w);
}

// ---------------- kernel 0a: convert x fp32 -> fp16 ----------------
__global__ void cvt_x(const float* __restrict__ x, f16* __restrict__ xh) {
    size_t i = ((size_t)blockIdx.x * 256 + threadIdx.x) * 8;
    float4 a = *(const float4*)(x + i);
    float4 b = *(const float4*)(x + i + 4);
    half8 h = {(f16)a.x,(f16)a.y,(f16)a.z,(f16)a.w,
               (f16)b.x,(f16)b.y,(f16)b.z,(f16)b.w};
    *(half8*)(xh + i) = h;
}

// ------------- kernel 0b: transpose+convert Wk,Wq -> wt[2][F][D] -------------
__global__ void cvt_w(const float* __restrict__ Wk, const float* __restrict__ Wq,
                      f16* __restrict__ wt) {
    __shared__ float tile[32][33];
    const float* W = (blockIdx.z == 0) ? Wk : Wq;
    f16* outp = wt + (size_t)blockIdx.z * D_ * F_;
    int x0 = blockIdx.x * 32, y0 = blockIdx.y * 32;
    int tx = threadIdx.x, ty = threadIdx.y;
#pragma unroll
    for (int i = 0; i < 4; i++)
        tile[ty + i*8][tx] = W[(size_t)(y0 + ty + i*8) * F_ + x0 + tx];
    __syncthreads();
#pragma unroll
    for (int i = 0; i < 4; i++)
        outp[(size_t)(x0 + ty + i*8) * D_ + y0 + tx] = (f16)tile[tx][ty + i*8];
}

// ------------- kernel 1: fused Q/K GEMM + tanh + diag-dot partials -------------
__launch_bounds__(256, 2)
__global__ void score_gemm(const f16* __restrict__ xh, const f16* __restrict__ wt,
                           float* __restrict__ part) {
    __shared__ __align__(16) f16 Xs[TB][32];    // 8 KB, rows 64B, NO pad (gload_lds linear)
    __shared__ __align__(16) f16 WsK[FB][32];   // 8 KB
    __shared__ __align__(16) f16 WsQ[FB][32];   // 8 KB
    __shared__ float sred[2][TB];

    const int tok0 = blockIdx.x * TB;
    const int f0   = blockIdx.y * FB;
    const int t    = threadIdx.x;
    const int lane = t & 63;
    const int w    = t >> 6;
    const int wr   = (w >> 1) * 64;
    const int wc   = (w & 1) * 64;

    const int c0 = t, c1 = t + 256;
    const int r0 = c0 >> 2, q0 = (c0 & 3) * 8;
    const int r1 = c1 >> 2, q1 = (c1 & 3) * 8;
    char* ldsX = (char*)Xs  + (size_t)(t - lane) * 16;
    char* ldsK = (char*)WsK + (size_t)(t - lane) * 16;
    char* ldsQ = (char*)WsQ + (size_t)(t - lane) * 16;

    const f16* wK = wt + (size_t)f0 * D_;
    const f16* wQ = wt + (size_t)D_ * F_ + (size_t)f0 * D_;

    f32x4 accQ[4][4] = {};
    f32x4 accK[4][4] = {};

    for (int k0 = 0; k0 < D_; k0 += BK) {
        __syncthreads();
        gload_lds16(xh + (size_t)(tok0 + r0) * D_ + k0 + q0, ldsX);
        gload_lds16(xh + (size_t)(tok0 + r1) * D_ + k0 + q1, ldsX + 4096);
        gload_lds16(wK + (size_t)r0 * D_ + k0 + q0, ldsK);
        gload_lds16(wK + (size_t)r1 * D_ + k0 + q1, ldsK + 4096);
        gload_lds16(wQ + (size_t)r0 * D_ + k0 + q0, ldsQ);
        gload_lds16(wQ + (size_t)r1 * D_ + k0 + q1, ldsQ + 4096);
        __syncthreads();

        half8 aF[4], bK[4], bQ[4];
#pragma unroll
        for (int m = 0; m < 4; ++m)
            aF[m] = *(const half8*)&Xs[wr + m * 16 + (lane & 15)][(lane >> 4) * 8];
#pragma unroll
        for (int n = 0; n < 4; ++n) {
            bK[n] = *(const half8*)&WsK[wc + n * 16 + (lane & 15)][(lane >> 4) * 8];
            bQ[n] = *(const half8*)&WsQ[wc + n * 16 + (lane & 15)][(lane >> 4) * 8];
        }
#pragma unroll
        for (int n = 0; n < 4; ++n)
#pragma unroll
            for (int m = 0; m < 4; ++m) {
                accK[m][n] = __builtin_amdgcn_mfma_f32_16x16x32_f16(aF[m], bK[n], accK[m][n], 0, 0, 0);
                accQ[m][n] = __builtin_amdgcn_mfma_f32_16x16x32_f16(aF[m], bQ[n], accQ[m][n], 0, 0, 0);
            }
    }

#pragma unroll
    for (int m = 0; m < 4; ++m) {
        float s[4] = {0.f, 0.f, 0.f, 0.f};
#pragma unroll
        for (int n = 0; n < 4; ++n)
#pragma unroll
            for (int j = 0; j < 4; ++j)
                s[j] += tanhf(accQ[m][n][j]) * tanhf(accK[m][n][j]);
#pragma unroll
        for (int j = 0; j < 4; ++j) {
            s[j] += __shfl_xor(s[j], 1);
            s[j] += __shfl_xor(s[j], 2);
            s[j] += __shfl_xor(s[j], 4);
            s[j] += __shfl_xor(s[j], 8);
        }
        if ((lane & 15) == 0) {
            int g = lane >> 4;
#pragma unroll
            for (int j = 0; j < 4; ++j)
                sred[w & 1][wr + m * 16 + g * 4 + j] = s[j];
        }
    }
    __syncthreads();
    if (t < TB)
        part[(size_t)blockIdx.y * TOK + tok0 + t] = sred[0][t] + sred[1][t];
}

// ------------- kernel 2: per-batch softmax over S -------------
__global__ void softmax_k(const float* __restrict__ part, float* __restrict__ out) {
    __shared__ float sc[S_];
    __shared__ float red[256];
    const int b = blockIdx.x, t = threadIdx.x;
    float lmax = -1e30f;
    for (int i = t; i < S_; i += 256) {
        float s = 0.f;
#pragma unroll
        for (int fb = 0; fb < NFB; ++fb) s += part[(size_t)fb * TOK + b * S_ + i];
        sc[i] = s;
        lmax = fmaxf(lmax, s);
    }
    red[t] = lmax; __syncthreads();
    for (int o = 128; o > 0; o >>= 1) { if (t < o) red[t] = fmaxf(red[t], red[t + o]); __syncthreads(); }
    const float mx = red[0]; __syncthreads();
    float lsum = 0.f;
    for (int i = t; i < S_; i += 256) { float e = expf(sc[i] - mx); sc[i] = e; lsum += e; }
    red[t] = lsum; __syncthreads();
    for (int o = 128; o > 0; o >>= 1) { if (t < o) red[t] += red[t + o]; __syncthreads(); }
    const float inv = 1.0f / red[0];
    for (int i = t; i < S_; i += 256)
        out[(size_t)B_ * F_ + (size_t)b * S_ + i] = sc[i] * inv;
}

// ------------- kernel 3: sparse value pass, one block per (b,chunk), all f -------------
// thread t owns f columns 4t..4t+3; groups of 4 tokens zero-padded (no hot-loop branches)
__launch_bounds__(256)
__global__ void value_k3(const float* __restrict__ x, const float* __restrict__ Wv,
                         const float* __restrict__ p_in, float* __restrict__ vpart) {
    __shared__ __align__(16) float xs[4][D_];   // 16 KB
    __shared__ float ps[CS];
    __shared__ int   idxs[CS];
    __shared__ int   wsum[4];
    const int b = blockIdx.x, c = blockIdx.y;
    const int t = threadIdx.x, lane = t & 63, w = t >> 6;
    const int s0 = c * CS;

    // deterministic parallel compaction (ballot + popcount prefix)
    float p = p_in[(size_t)b * S_ + s0 + t];
    bool flag = p > 1e-7f;
    unsigned long long mask = __ballot(flag);
    if (lane == 0) wsum[w] = __popcll(mask);
    __syncthreads();
    int base = 0;
#pragma unroll
    for (int i = 0; i < 4; ++i) if (i < w) base += wsum[i];
    const int cnt = wsum[0] + wsum[1] + wsum[2] + wsum[3];
    if (flag) {
        int pos = base + __popcll(mask & ((1ull << lane) - 1ull));
        idxs[pos] = s0 + t;
        ps[pos] = p;
    }
    __syncthreads();

    float4 acc = {0.f, 0.f, 0.f, 0.f};
    for (int g = 0; g < cnt; g += 4) {
        __syncthreads();
#pragma unroll
        for (int r = 0; r < 4; ++r) {
            float4 v = {0.f, 0.f, 0.f, 0.f};
            if (g + r < cnt)
                v = ((const float4*)(x + ((size_t)b * S_ + idxs[g + r]) * D_))[t];
            ((float4*)xs[r])[t] = v;          // full 4KB row per r
        }
        __syncthreads();
        float4 a0 = {0,0,0,0}, a1 = {0,0,0,0}, a2 = {0,0,0,0}, a3 = {0,0,0,0};
#pragma unroll 2
        for (int dq = 0; dq < D_ / 4; ++dq) {
            const float* wr = Wv + (size_t)dq * 4 * F_;
            float4 wv0 = ((const float4*)(wr        ))[t];
            float4 wv1 = ((const float4*)(wr + F_   ))[t];
            float4 wv2 = ((const float4*)(wr + 2*F_ ))[t];
            float4 wv3 = ((const float4*)(wr + 3*F_ ))[t];
            float4 x0 = ((const float4*)xs[0])[dq];
            float4 x1 = ((const float4*)xs[1])[dq];
            float4 x2 = ((const float4*)xs[2])[dq];
            float4 x3 = ((const float4*)xs[3])[dq];
            fma4(a0, x0.x, wv0); fma4(a0, x0.y, wv1); fma4(a0, x0.z, wv2); fma4(a0, x0.w, wv3);
            fma4(a1, x1.x, wv0); fma4(a1, x1.y, wv1); fma4(a1, x1.z, wv2); fma4(a1, x1.w, wv3);
            fma4(a2, x2.x, wv0); fma4(a2, x2.y, wv1); fma4(a2, x2.z, wv2); fma4(a2, x2.w, wv3);
            fma4(a3, x3.x, wv0); fma4(a3, x3.y, wv1); fma4(a3, x3.z, wv2); fma4(a3, x3.w, wv3);
        }
        int rem = cnt - g;
        if (rem > 0) wtanh4(acc, ps[g + 0], a0);
        if (rem > 1) wtanh4(acc, ps[g + 1], a1);
        if (rem > 2) wtanh4(acc, ps[g + 2], a2);
        if (rem > 3) wtanh4(acc, ps[g + 3], a3);
    }
    ((float4*)(vpart + ((size_t)c * B_ + b) * F_))[t] = acc;
}

// ------------- kernel 4: reduce chunk partials -------------
__global__ void value_red(const float* __restrict__ vpart, float* __restrict__ out) {
    int i = blockIdx.x * 256 + threadIdx.x;
    float s = 0.f;
#pragma unroll
    for (int c = 0; c < NS; ++c) s += vpart[(size_t)c * B_ * F_ + i];
    out[i] = s;
}

extern "C" void kernel_launch(void* const* d_in, const int* in_sizes, int n_in,
                              void* d_out, int out_size, void* d_ws, size_t ws_size,
                              hipStream_t stream) {
    const float* x  = (const float*)d_in[0];
    const float* Wk = (const float*)d_in[1];
    const float* Wq = (const float*)d_in[2];
    const float* Wv = (const float*)d_in[3];
    float* out = (float*)d_out;
    char* ws = (char*)d_ws;

    f16*   xh   = (f16*)ws;                                              // 128 MB
    f16*   wt   = (f16*)(ws + (size_t)TOK * D_ * 2);                     // 4 MB
    float* part = (float*)(ws + (size_t)TOK * D_ * 2 + 2 * (size_t)D_ * F_ * 2); // 2 MB

    cvt_x<<<TOK * D_ / 8 / 256, 256, 0, stream>>>(x, xh);
    cvt_w<<<dim3(32, 32, 2), dim3(32, 8), 0, stream>>>(Wk, Wq, wt);
    score_gemm<<<dim3(TOK / TB, NFB), 256, 0, stream>>>(xh, wt, part);
    softmax_k<<<B_, 256, 0, stream>>>(part, out);
    float* vpart = part;
    const float* p_in = out + (size_t)B_ * F_;
    value_k3<<<dim3(B_, NS), 256, 0, stream>>>(x, Wv, p_in, vpart);
    value_red<<<B_ * F_ / 256, 256, 0, stream>>>(vpart, out);
}

// Round 5
// 649.943 us; speedup vs baseline: 2.6722x; 1.0184x over previous
//
#include <hip/hip_runtime.h>
#include <hip/hip_bf16.h>
#include <math.h>
#include <stdint.h>

typedef _Float16 f16;
typedef _Float16 half8 __attribute__((ext_vector_type(8)));
typedef float f32x4 __attribute__((ext_vector_type(4)));

#define B_ 16
#define S_ 4096
#define D_ 1024
#define F_ 1024
#define TOK (B_*S_)
#define TB2 256        // token tile
#define FB 128         // f tile
#define NFB (F_/FB)    // 8
#define BK2 64         // K step
#define NT (D_/BK2)    // 16
#define NS 16
#define CS (S_/NS)     // 256

// async global->LDS, 16B per lane; lds dest must be wave-uniform base (+lane*16 by HW)
__device__ __forceinline__ void gload_lds16(const void* g, void* l) {
    __builtin_amdgcn_global_load_lds(
        (__attribute__((address_space(1))) const unsigned int*)(unsigned long long)(uintptr_t)g,
        (__attribute__((address_space(3))) unsigned int*)(unsigned int)(uintptr_t)l,
        16, 0, 0);
}

__device__ __forceinline__ void fma4(float4& a, float s, const float4& wv) {
    a.x += s * wv.x; a.y += s * wv.y; a.z += s * wv.z; a.w += s * wv.w;
}
__device__ __forceinline__ void wtanh4(float4& acc, float pw, const float4& a) {
    acc.x += pw * tanhf(a.x); acc.y += pw * tanhf(a.y);
    acc.z += pw * tanhf(a.z); acc.w += pw * tanhf(a.w);
}

// ---------------- kernel 0a: convert x fp32 -> fp16 ----------------
__global__ void cvt_x(const float* __restrict__ x, f16* __restrict__ xh) {
    size_t i = ((size_t)blockIdx.x * 256 + threadIdx.x) * 8;
    float4 a = *(const float4*)(x + i);
    float4 b = *(const float4*)(x + i + 4);
    half8 h = {(f16)a.x,(f16)a.y,(f16)a.z,(f16)a.w,
               (f16)b.x,(f16)b.y,(f16)b.z,(f16)b.w};
    *(half8*)(xh + i) = h;
}

// ------------- kernel 0b: transpose+convert Wk,Wq -> wt[2][F][D] -------------
__global__ void cvt_w(const float* __restrict__ Wk, const float* __restrict__ Wq,
                      f16* __restrict__ wt) {
    __shared__ float tile[32][33];
    const float* W = (blockIdx.z == 0) ? Wk : Wq;
    f16* outp = wt + (size_t)blockIdx.z * D_ * F_;
    int x0 = blockIdx.x * 32, y0 = blockIdx.y * 32;
    int tx = threadIdx.x, ty = threadIdx.y;
#pragma unroll
    for (int i = 0; i < 4; i++)
        tile[ty + i*8][tx] = W[(size_t)(y0 + ty + i*8) * F_ + x0 + tx];
    __syncthreads();
#pragma unroll
    for (int i = 0; i < 4; i++)
        outp[(size_t)(x0 + ty + i*8) * D_ + y0 + tx] = (f16)tile[tx][ty + i*8];
}

// ------------- kernel 1: fused Q/K GEMM + tanh + diag-dot partials -------------
// 256x128 tile, 8 waves (4 tok-groups x 2 f-groups, each 64x64 per matrix),
// BK=64, double-buffered linear LDS (2x64KB) staged via global_load_lds w16,
// stage(t+1) issued BEFORE compute(t), ONE barrier per K-step (T3 minimum-2ph).
__launch_bounds__(512, 2)
__global__ void score_gemm(const f16* __restrict__ xh, const f16* __restrict__ wt,
                           float* __restrict__ part) {
    __shared__ __align__(16) f16 Xs[2][TB2][BK2];   // 2 x 32 KB
    __shared__ __align__(16) f16 Ks[2][FB][BK2];    // 2 x 16 KB
    __shared__ __align__(16) f16 Qs[2][FB][BK2];    // 2 x 16 KB
    __shared__ float sred[2][TB2];

    const int f0   = blockIdx.x * FB;     // f-block is FAST grid axis (L2/L3 reuse of X)
    const int tok0 = blockIdx.y * TB2;
    const int t    = threadIdx.x;         // 0..511
    const int lane = t & 63;
    const int w    = t >> 6;              // 0..7
    const int wr   = (w >> 1) * 64;       // token offset of wave sub-tile
    const int wc   = (w & 1) * 64;        // f offset of wave sub-tile

    const f16* wK = wt + (size_t)f0 * D_;
    const f16* wQ = wt + (size_t)D_ * F_ + (size_t)f0 * D_;

    // staging: chunk c (16B) -> row c>>3, col-quad c&7 (rows are 128B linear)
#define STAGE(bi, k0) do {                                                         \
        char* xb = (char*)Xs[bi] + w * 1024;                                       \
        char* kb = (char*)Ks[bi] + w * 1024;                                       \
        char* qb = (char*)Qs[bi] + w * 1024;                                       \
        _Pragma("unroll")                                                          \
        for (int i_ = 0; i_ < 4; ++i_) {                                           \
            int c_ = i_ * 512 + t;                                                 \
            gload_lds16(xh + (size_t)(tok0 + (c_ >> 3)) * D_ + (k0) + (c_ & 7) * 8,\
                        xb + i_ * 8192);                                           \
        }                                                                          \
        _Pragma("unroll")                                                          \
        for (int i_ = 0; i_ < 2; ++i_) {                                           \
            int c_ = i_ * 512 + t;                                                 \
            gload_lds16(wK + (size_t)(c_ >> 3) * D_ + (k0) + (c_ & 7) * 8,         \
                        kb + i_ * 8192);                                           \
            gload_lds16(wQ + (size_t)(c_ >> 3) * D_ + (k0) + (c_ & 7) * 8,         \
                        qb + i_ * 8192);                                           \
        }                                                                          \
    } while (0)

    f32x4 accQ[4][4] = {};
    f32x4 accK[4][4] = {};

    STAGE(0, 0);
    __syncthreads();          // drains vmcnt(0) implicitly
    int cur = 0;

    for (int kt = 0; kt < NT; ++kt) {
        if (kt + 1 < NT) STAGE(cur ^ 1, (kt + 1) * BK2);   // prefetch next K-tile

#pragma unroll
        for (int ks = 0; ks < 2; ++ks) {
            half8 aF[4], bKf[4], bQf[4];
#pragma unroll
            for (int m = 0; m < 4; ++m)
                aF[m] = *(const half8*)&Xs[cur][wr + m * 16 + (lane & 15)][ks * 32 + (lane >> 4) * 8];
#pragma unroll
            for (int n = 0; n < 4; ++n) {
                bKf[n] = *(const half8*)&Ks[cur][wc + n * 16 + (lane & 15)][ks * 32 + (lane >> 4) * 8];
                bQf[n] = *(const half8*)&Qs[cur][wc + n * 16 + (lane & 15)][ks * 32 + (lane >> 4) * 8];
            }
#pragma unroll
            for (int n = 0; n < 4; ++n)
#pragma unroll
                for (int m = 0; m < 4; ++m) {
                    accK[m][n] = __builtin_amdgcn_mfma_f32_16x16x32_f16(aF[m], bKf[n], accK[m][n], 0, 0, 0);
                    accQ[m][n] = __builtin_amdgcn_mfma_f32_16x16x32_f16(aF[m], bQf[n], accQ[m][n], 0, 0, 0);
                }
        }
        __syncthreads();      // one barrier per K-step: reads of cur done + stage(cur^1) drained
        cur ^= 1;
    }
#undef STAGE

    // epilogue: tanh, product, reduce over f within wave, combine the 2 f-wave-cols
#pragma unroll
    for (int m = 0; m < 4; ++m) {
        float s[4] = {0.f, 0.f, 0.f, 0.f};
#pragma unroll
        for (int n = 0; n < 4; ++n)
#pragma unroll
            for (int j = 0; j < 4; ++j)
                s[j] += tanhf(accQ[m][n][j]) * tanhf(accK[m][n][j]);
#pragma unroll
        for (int j = 0; j < 4; ++j) {
            s[j] += __shfl_xor(s[j], 1);
            s[j] += __shfl_xor(s[j], 2);
            s[j] += __shfl_xor(s[j], 4);
            s[j] += __shfl_xor(s[j], 8);
        }
        if ((lane & 15) == 0) {
            int g = lane >> 4;
#pragma unroll
            for (int j = 0; j < 4; ++j)
                sred[w & 1][wr + m * 16 + g * 4 + j] = s[j];
        }
    }
    __syncthreads();
    if (t < TB2)
        part[(size_t)blockIdx.x * TOK + tok0 + t] = sred[0][t] + sred[1][t];
}

// ------------- kernel 2: per-batch softmax over S -------------
__global__ void softmax_k(const float* __restrict__ part, float* __restrict__ out) {
    __shared__ float sc[S_];
    __shared__ float red[256];
    const int b = blockIdx.x, t = threadIdx.x;
    float lmax = -1e30f;
    for (int i = t; i < S_; i += 256) {
        float s = 0.f;
#pragma unroll
        for (int fb = 0; fb < NFB; ++fb) s += part[(size_t)fb * TOK + b * S_ + i];
        sc[i] = s;
        lmax = fmaxf(lmax, s);
    }
    red[t] = lmax; __syncthreads();
    for (int o = 128; o > 0; o >>= 1) { if (t < o) red[t] = fmaxf(red[t], red[t + o]); __syncthreads(); }
    const float mx = red[0]; __syncthreads();
    float lsum = 0.f;
    for (int i = t; i < S_; i += 256) { float e = expf(sc[i] - mx); sc[i] = e; lsum += e; }
    red[t] = lsum; __syncthreads();
    for (int o = 128; o > 0; o >>= 1) { if (t < o) red[t] += red[t + o]; __syncthreads(); }
    const float inv = 1.0f / red[0];
    for (int i = t; i < S_; i += 256)
        out[(size_t)B_ * F_ + (size_t)b * S_ + i] = sc[i] * inv;
}

// ------------- kernel 3: sparse value pass, one block per (b,chunk), all f -------------
__launch_bounds__(256)
__global__ void value_k3(const float* __restrict__ x, const float* __restrict__ Wv,
                         const float* __restrict__ p_in, float* __restrict__ vpart) {
    __shared__ __align__(16) float xs[4][D_];   // 16 KB
    __shared__ float ps[CS];
    __shared__ int   idxs[CS];
    __shared__ int   wsum[4];
    const int b = blockIdx.x, c = blockIdx.y;
    const int t = threadIdx.x, lane = t & 63, w = t >> 6;
    const int s0 = c * CS;

    float p = p_in[(size_t)b * S_ + s0 + t];
    bool flag = p > 1e-7f;
    unsigned long long mask = __ballot(flag);
    if (lane == 0) wsum[w] = __popcll(mask);
    __syncthreads();
    int base = 0;
#pragma unroll
    for (int i = 0; i < 4; ++i) if (i < w) base += wsum[i];
    const int cnt = wsum[0] + wsum[1] + wsum[2] + wsum[3];
    if (flag) {
        int pos = base + __popcll(mask & ((1ull << lane) - 1ull));
        idxs[pos] = s0 + t;
        ps[pos] = p;
    }
    __syncthreads();

    float4 acc = {0.f, 0.f, 0.f, 0.f};
    for (int g = 0; g < cnt; g += 4) {
        __syncthreads();
#pragma unroll
        for (int r = 0; r < 4; ++r) {
            float4 v = {0.f, 0.f, 0.f, 0.f};
            if (g + r < cnt)
                v = ((const float4*)(x + ((size_t)b * S_ + idxs[g + r]) * D_))[t];
            ((float4*)xs[r])[t] = v;
        }
        __syncthreads();
        float4 a0 = {0,0,0,0}, a1 = {0,0,0,0}, a2 = {0,0,0,0}, a3 = {0,0,0,0};
#pragma unroll 2
        for (int dq = 0; dq < D_ / 4; ++dq) {
            const float* wr = Wv + (size_t)dq * 4 * F_;
            float4 wv0 = ((const float4*)(wr        ))[t];
            float4 wv1 = ((const float4*)(wr + F_   ))[t];
            float4 wv2 = ((const float4*)(wr + 2*F_ ))[t];
            float4 wv3 = ((const float4*)(wr + 3*F_ ))[t];
            float4 x0 = ((const float4*)xs[0])[dq];
            float4 x1 = ((const float4*)xs[1])[dq];
            float4 x2 = ((const float4*)xs[2])[dq];
            float4 x3 = ((const float4*)xs[3])[dq];
            fma4(a0, x0.x, wv0); fma4(a0, x0.y, wv1); fma4(a0, x0.z, wv2); fma4(a0, x0.w, wv3);
            fma4(a1, x1.x, wv0); fma4(a1, x1.y, wv1); fma4(a1, x1.z, wv2); fma4(a1, x1.w, wv3);
            fma4(a2, x2.x, wv0); fma4(a2, x2.y, wv1); fma4(a2, x2.z, wv2); fma4(a2, x2.w, wv3);
            fma4(a3, x3.x, wv0); fma4(a3, x3.y, wv1); fma4(a3, x3.z, wv2); fma4(a3, x3.w, wv3);
        }
        int rem = cnt - g;
        if (rem > 0) wtanh4(acc, ps[g + 0], a0);
        if (rem > 1) wtanh4(acc, ps[g + 1], a1);
        if (rem > 2) wtanh4(acc, ps[g + 2], a2);
        if (rem > 3) wtanh4(acc, ps[g + 3], a3);
    }
    ((float4*)(vpart + ((size_t)c * B_ + b) * F_))[t] = acc;
}

// ------------- kernel 4: reduce chunk partials -------------
__global__ void value_red(const float* __restrict__ vpart, float* __restrict__ out) {
    int i = blockIdx.x * 256 + threadIdx.x;
    float s = 0.f;
#pragma unroll
    for (int c = 0; c < NS; ++c) s += vpart[(size_t)c * B_ * F_ + i];
    out[i] = s;
}

extern "C" void kernel_launch(void* const* d_in, const int* in_sizes, int n_in,
                              void* d_out, int out_size, void* d_ws, size_t ws_size,
                              hipStream_t stream) {
    const float* x  = (const float*)d_in[0];
    const float* Wk = (const float*)d_in[1];
    const float* Wq = (const float*)d_in[2];
    const float* Wv = (const float*)d_in[3];
    float* out = (float*)d_out;
    char* ws = (char*)d_ws;

    f16*   xh   = (f16*)ws;                                              // 128 MB
    f16*   wt   = (f16*)(ws + (size_t)TOK * D_ * 2);                     // 4 MB
    float* part = (float*)(ws + (size_t)TOK * D_ * 2 + 2 * (size_t)D_ * F_ * 2); // 2 MB

    cvt_x<<<TOK * D_ / 8 / 256, 256, 0, stream>>>(x, xh);
    cvt_w<<<dim3(32, 32, 2), dim3(32, 8), 0, stream>>>(Wk, Wq, wt);
    score_gemm<<<dim3(NFB, TOK / TB2), 512, 0, stream>>>(xh, wt, part);
    softmax_k<<<B_, 256, 0, stream>>>(part, out);
    float* vpart = part;
    const float* p_in = out + (size_t)B_ * F_;
    value_k3<<<dim3(B_, NS), 256, 0, stream>>>(x, Wv, p_in, vpart);
    value_red<<<B_ * F_ / 256, 256, 0, stream>>>(vpart, out);
}

// Round 6
// 634.763 us; speedup vs baseline: 2.7361x; 1.0239x over previous
//
#include <hip/hip_runtime.h>
#include <hip/hip_bf16.h>
#include <math.h>
#include <stdint.h>

typedef _Float16 f16;
typedef _Float16 half8 __attribute__((ext_vector_type(8)));
typedef float f32x4 __attribute__((ext_vector_type(4)));

#define B_ 16
#define S_ 4096
#define D_ 1024
#define F_ 1024
#define TOK (B_*S_)
#define TB2 256        // token tile
#define FB 128         // f tile
#define NFB (F_/FB)    // 8
#define BK3 32         // K step
#define NT3 (D_/BK3)   // 32
#define NS 16
#define CS (S_/NS)     // 256

// async global->LDS, 16B per lane; lds dest = wave-uniform base + lane*16 (HW)
__device__ __forceinline__ void gload_lds16(const void* g, void* l) {
    __builtin_amdgcn_global_load_lds(
        (__attribute__((address_space(1))) const unsigned int*)(unsigned long long)(uintptr_t)g,
        (__attribute__((address_space(3))) unsigned int*)(unsigned int)(uintptr_t)l,
        16, 0, 0);
}

__device__ __forceinline__ void fma4(float4& a, float s, const float4& wv) {
    a.x += s * wv.x; a.y += s * wv.y; a.z += s * wv.z; a.w += s * wv.w;
}
__device__ __forceinline__ void wtanh4(float4& acc, float pw, const float4& a) {
    acc.x += pw * tanhf(a.x); acc.y += pw * tanhf(a.y);
    acc.z += pw * tanhf(a.z); acc.w += pw * tanhf(a.w);
}

// ---------------- kernel 0a: convert x fp32 -> fp16 ----------------
__global__ void cvt_x(const float* __restrict__ x, f16* __restrict__ xh) {
    size_t i = ((size_t)blockIdx.x * 256 + threadIdx.x) * 8;
    float4 a = *(const float4*)(x + i);
    float4 b = *(const float4*)(x + i + 4);
    half8 h = {(f16)a.x,(f16)a.y,(f16)a.z,(f16)a.w,
               (f16)b.x,(f16)b.y,(f16)b.z,(f16)b.w};
    *(half8*)(xh + i) = h;
}

// ------------- kernel 0b: transpose+convert Wk,Wq -> wt[2][F][D] -------------
__global__ void cvt_w(const float* __restrict__ Wk, const float* __restrict__ Wq,
                      f16* __restrict__ wt) {
    __shared__ float tile[32][33];
    const float* W = (blockIdx.z == 0) ? Wk : Wq;
    f16* outp = wt + (size_t)blockIdx.z * D_ * F_;
    int x0 = blockIdx.x * 32, y0 = blockIdx.y * 32;
    int tx = threadIdx.x, ty = threadIdx.y;
#pragma unroll
    for (int i = 0; i < 4; i++)
        tile[ty + i*8][tx] = W[(size_t)(y0 + ty + i*8) * F_ + x0 + tx];
    __syncthreads();
#pragma unroll
    for (int i = 0; i < 4; i++)
        outp[(size_t)(x0 + ty + i*8) * D_ + y0 + tx] = (f16)tile[tx][ty + i*8];
}

// ------------- kernel 1: fused Q/K GEMM + tanh + diag-dot partials -------------
// 256x128 tile, 8 waves (4 tok x 2 f groups, each 64x64 for BOTH Q,K).
// BK=32, 4 LDS slots, prefetch 3 tiles ahead, counted vmcnt(8) + ONE raw
// s_barrier per K-tile (T3+T4). Quad-XOR LDS swizzle both-sides (T2).
// setprio around MFMA clusters (T5). XCD-chunked block swizzle (T1).
__launch_bounds__(512, 2)
__global__ void score_gemm(const f16* __restrict__ xh, const f16* __restrict__ wt,
                           float* __restrict__ part) {
    __shared__ __align__(16) f16 Xs[4][TB2 * BK3];   // 4 x 16 KB
    __shared__ __align__(16) f16 Ks[4][FB * BK3];    // 4 x 8 KB
    __shared__ __align__(16) f16 Qs[4][FB * BK3];    // 4 x 8 KB
    __shared__ float sred[2][TB2];

    // T1: bijective XCD chunk swizzle (2048 blocks, 8 XCDs -> 256 each)
    const int hid  = blockIdx.x + blockIdx.y * NFB;
    const int orig = (hid & 7) * 256 + (hid >> 3);
    const int fb   = orig & 7;
    const int f0   = fb * FB;
    const int tok0 = (orig >> 3) * TB2;

    const int t    = threadIdx.x;     // 0..511
    const int lane = t & 63;
    const int w    = t >> 6;          // 0..7
    const int wr   = (w >> 1) * 64;   // token offset of wave sub-tile
    const int wc   = (w & 1) * 64;    // f offset of wave sub-tile

    const f16* wK = wt + (size_t)f0 * D_;
    const f16* wQ = wt + (size_t)D_ * F_ + (size_t)f0 * D_;

    // ---- staging constants (loop-invariant). chunk c -> row=c>>2, q=c&3,
    // source quad pre-swizzled: qsrc = q ^ ((row>>1)&3)  (rule #21 involution)
    const int cX0 = t, cX1 = t + 512;
    const int rX0 = cX0 >> 2, rX1 = cX1 >> 2;
    const int qX0 = (cX0 & 3) ^ ((rX0 >> 1) & 3);
    const int qX1 = (cX1 & 3) ^ ((rX1 >> 1) & 3);
    const f16* srcX0 = xh + (size_t)(tok0 + rX0) * D_ + qX0 * 8;
    const f16* srcX1 = xh + (size_t)(tok0 + rX1) * D_ + qX1 * 8;
    const int rW = t >> 2;
    const int qW = (t & 3) ^ ((rW >> 1) & 3);
    const f16* srcK = wK + (size_t)rW * D_ + qW * 8;
    const f16* srcQ = wQ + (size_t)rW * D_ + qW * 8;
    const int wbase = w * 1024;       // wave-uniform LDS byte base for staging

    // ---- fragment read offsets (f16 elems, loop-invariant; swizzled read)
    int offA[4], offB[4];
#pragma unroll
    for (int m = 0; m < 4; ++m) {
        int row = wr + m * 16 + (lane & 15);
        int q   = (lane >> 4) ^ ((row >> 1) & 3);
        offA[m] = row * 32 + q * 8;
    }
#pragma unroll
    for (int n = 0; n < 4; ++n) {
        int row = wc + n * 16 + (lane & 15);
        int q   = (lane >> 4) ^ ((row >> 1) & 3);
        offB[n] = row * 32 + q * 8;
    }

#define STAGE_X(slot, kof) do {                                   \
        char* xb = (char*)Xs[slot] + wbase;                       \
        gload_lds16(srcX0 + (kof), xb);                           \
        gload_lds16(srcX1 + (kof), xb + 8192);                    \
    } while (0)
#define STAGE_W(slot, kof) do {                                   \
        gload_lds16(srcK + (kof), (char*)Ks[slot] + wbase);       \
        gload_lds16(srcQ + (kof), (char*)Qs[slot] + wbase);       \
    } while (0)

    f32x4 accQ[4][4] = {};
    f32x4 accK[4][4] = {};

    // prologue: stage tiles 0,1,2 (12 loads/wave), then drain tile-0's 4
    STAGE_X(0, 0);  STAGE_W(0, 0);
    STAGE_X(1, 32); STAGE_W(1, 32);
    STAGE_X(2, 64); STAGE_W(2, 64);
    asm volatile("s_waitcnt vmcnt(8)" ::: "memory");
    __builtin_amdgcn_s_barrier();
    __builtin_amdgcn_sched_barrier(0);

    for (int kt = 0; kt < NT3; ++kt) {
        const int slot  = kt & 3;
        const int pslot = (kt + 3) & 3;
        const int kof   = (kt + 3) * BK3;
        const f16* Xb = Xs[slot];
        const f16* Kb = Ks[slot];
        const f16* Qb = Qs[slot];

        // ---- phase 1: issue X prefetch, read A+BK frags, 16 MFMA (accK)
        if (kt < NT3 - 3) STAGE_X(pslot, kof);
        half8 aF[4], bKf[4];
#pragma unroll
        for (int m = 0; m < 4; ++m) aF[m]  = *(const half8*)(Xb + offA[m]);
#pragma unroll
        for (int n = 0; n < 4; ++n) bKf[n] = *(const half8*)(Kb + offB[n]);
        __builtin_amdgcn_s_setprio(1);
#pragma unroll
        for (int n = 0; n < 4; ++n)
#pragma unroll
            for (int m = 0; m < 4; ++m)
                accK[m][n] = __builtin_amdgcn_mfma_f32_16x16x32_f16(aF[m], bKf[n], accK[m][n], 0, 0, 0);
        __builtin_amdgcn_s_setprio(0);

        // ---- phase 2: issue W prefetch, read BQ frags, 16 MFMA (accQ)
        if (kt < NT3 - 3) STAGE_W(pslot, kof);
        half8 bQf[4];
#pragma unroll
        for (int n = 0; n < 4; ++n) bQf[n] = *(const half8*)(Qb + offB[n]);
        __builtin_amdgcn_s_setprio(1);
#pragma unroll
        for (int n = 0; n < 4; ++n)
#pragma unroll
            for (int m = 0; m < 4; ++m)
                accQ[m][n] = __builtin_amdgcn_mfma_f32_16x16x32_f16(aF[m], bQf[n], accQ[m][n], 0, 0, 0);
        __builtin_amdgcn_s_setprio(0);

        // ---- tile boundary: counted vmcnt (never 0 in main loop) + raw barrier
        if (kt < NT3 - 3) {
            asm volatile("s_waitcnt vmcnt(8)" ::: "memory");
        } else if (kt == NT3 - 3) {
            asm volatile("s_waitcnt vmcnt(4)" ::: "memory");
        } else if (kt == NT3 - 2) {
            asm volatile("s_waitcnt vmcnt(0)" ::: "memory");
        }
        if (kt < NT3 - 1) {
            __builtin_amdgcn_s_barrier();
            __builtin_amdgcn_sched_barrier(0);
        }
    }
#undef STAGE_X
#undef STAGE_W

    // epilogue: tanh, product, reduce over f within wave, combine 2 f-wave-cols
#pragma unroll
    for (int m = 0; m < 4; ++m) {
        float s[4] = {0.f, 0.f, 0.f, 0.f};
#pragma unroll
        for (int n = 0; n < 4; ++n)
#pragma unroll
            for (int j = 0; j < 4; ++j)
                s[j] += tanhf(accQ[m][n][j]) * tanhf(accK[m][n][j]);
#pragma unroll
        for (int j = 0; j < 4; ++j) {
            s[j] += __shfl_xor(s[j], 1);
            s[j] += __shfl_xor(s[j], 2);
            s[j] += __shfl_xor(s[j], 4);
            s[j] += __shfl_xor(s[j], 8);
        }
        if ((lane & 15) == 0) {
            int g = lane >> 4;
#pragma unroll
            for (int j = 0; j < 4; ++j)
                sred[w & 1][wr + m * 16 + g * 4 + j] = s[j];
        }
    }
    __syncthreads();
    if (t < TB2)
        part[(size_t)fb * TOK + tok0 + t] = sred[0][t] + sred[1][t];
}

// ------------- kernel 2: per-batch softmax over S -------------
__global__ void softmax_k(const float* __restrict__ part, float* __restrict__ out) {
    __shared__ float sc[S_];
    __shared__ float red[256];
    const int b = blockIdx.x, t = threadIdx.x;
    float lmax = -1e30f;
    for (int i = t; i < S_; i += 256) {
        float s = 0.f;
#pragma unroll
        for (int fb = 0; fb < NFB; ++fb) s += part[(size_t)fb * TOK + b * S_ + i];
        sc[i] = s;
        lmax = fmaxf(lmax, s);
    }
    red[t] = lmax; __syncthreads();
    for (int o = 128; o > 0; o >>= 1) { if (t < o) red[t] = fmaxf(red[t], red[t + o]); __syncthreads(); }
    const float mx = red[0]; __syncthreads();
    float lsum = 0.f;
    for (int i = t; i < S_; i += 256) { float e = expf(sc[i] - mx); sc[i] = e; lsum += e; }
    red[t] = lsum; __syncthreads();
    for (int o = 128; o > 0; o >>= 1) { if (t < o) red[t] += red[t + o]; __syncthreads(); }
    const float inv = 1.0f / red[0];
    for (int i = t; i < S_; i += 256)
        out[(size_t)B_ * F_ + (size_t)b * S_ + i] = sc[i] * inv;
}

// ------------- kernel 3: sparse value pass, one block per (b,chunk), all f -------------
__launch_bounds__(256)
__global__ void value_k3(const float* __restrict__ x, const float* __restrict__ Wv,
                         const float* __restrict__ p_in, float* __restrict__ vpart) {
    __shared__ __align__(16) float xs[4][D_];   // 16 KB
    __shared__ float ps[CS];
    __shared__ int   idxs[CS];
    __shared__ int   wsum[4];
    const int b = blockIdx.x, c = blockIdx.y;
    const int t = threadIdx.x, lane = t & 63, w = t >> 6;
    const int s0 = c * CS;

    float p = p_in[(size_t)b * S_ + s0 + t];
    bool flag = p > 1e-7f;
    unsigned long long mask = __ballot(flag);
    if (lane == 0) wsum[w] = __popcll(mask);
    __syncthreads();
    int base = 0;
#pragma unroll
    for (int i = 0; i < 4; ++i) if (i < w) base += wsum[i];
    const int cnt = wsum[0] + wsum[1] + wsum[2] + wsum[3];
    if (flag) {
        int pos = base + __popcll(mask & ((1ull << lane) - 1ull));
        idxs[pos] = s0 + t;
        ps[pos] = p;
    }
    __syncthreads();

    float4 acc = {0.f, 0.f, 0.f, 0.f};
    for (int g = 0; g < cnt; g += 4) {
        __syncthreads();
#pragma unroll
        for (int r = 0; r < 4; ++r) {
            float4 v = {0.f, 0.f, 0.f, 0.f};
            if (g + r < cnt)
                v = ((const float4*)(x + ((size_t)b * S_ + idxs[g + r]) * D_))[t];
            ((float4*)xs[r])[t] = v;
        }
        __syncthreads();
        float4 a0 = {0,0,0,0}, a1 = {0,0,0,0}, a2 = {0,0,0,0}, a3 = {0,0,0,0};
#pragma unroll 2
        for (int dq = 0; dq < D_ / 4; ++dq) {
            const float* wr = Wv + (size_t)dq * 4 * F_;
            float4 wv0 = ((const float4*)(wr        ))[t];
            float4 wv1 = ((const float4*)(wr + F_   ))[t];
            float4 wv2 = ((const float4*)(wr + 2*F_ ))[t];
            float4 wv3 = ((const float4*)(wr + 3*F_ ))[t];
            float4 x0 = ((const float4*)xs[0])[dq];
            float4 x1 = ((const float4*)xs[1])[dq];
            float4 x2 = ((const float4*)xs[2])[dq];
            float4 x3 = ((const float4*)xs[3])[dq];
            fma4(a0, x0.x, wv0); fma4(a0, x0.y, wv1); fma4(a0, x0.z, wv2); fma4(a0, x0.w, wv3);
            fma4(a1, x1.x, wv0); fma4(a1, x1.y, wv1); fma4(a1, x1.z, wv2); fma4(a1, x1.w, wv3);
            fma4(a2, x2.x, wv0); fma4(a2, x2.y, wv1); fma4(a2, x2.z, wv2); fma4(a2, x2.w, wv3);
            fma4(a3, x3.x, wv0); fma4(a3, x3.y, wv1); fma4(a3, x3.z, wv2); fma4(a3, x3.w, wv3);
        }
        int rem = cnt - g;
        if (rem > 0) wtanh4(acc, ps[g + 0], a0);
        if (rem > 1) wtanh4(acc, ps[g + 1], a1);
        if (rem > 2) wtanh4(acc, ps[g + 2], a2);
        if (rem > 3) wtanh4(acc, ps[g + 3], a3);
    }
    ((float4*)(vpart + ((size_t)c * B_ + b) * F_))[t] = acc;
}

// ------------- kernel 4: reduce chunk partials -------------
__global__ void value_red(const float* __restrict__ vpart, float* __restrict__ out) {
    int i = blockIdx.x * 256 + threadIdx.x;
    float s = 0.f;
#pragma unroll
    for (int c = 0; c < NS; ++c) s += vpart[(size_t)c * B_ * F_ + i];
    out[i] = s;
}

extern "C" void kernel_launch(void* const* d_in, const int* in_sizes, int n_in,
                              void* d_out, int out_size, void* d_ws, size_t ws_size,
                              hipStream_t stream) {
    const float* x  = (const float*)d_in[0];
    const float* Wk = (const float*)d_in[1];
    const float* Wq = (const float*)d_in[2];
    const float* Wv = (const float*)d_in[3];
    float* out = (float*)d_out;
    char* ws = (char*)d_ws;

    f16*   xh   = (f16*)ws;                                              // 128 MB
    f16*   wt   = (f16*)(ws + (size_t)TOK * D_ * 2);                     // 4 MB
    float* part = (float*)(ws + (size_t)TOK * D_ * 2 + 2 * (size_t)D_ * F_ * 2); // 2 MB

    cvt_x<<<TOK * D_ / 8 / 256, 256, 0, stream>>>(x, xh);
    cvt_w<<<dim3(32, 32, 2), dim3(32, 8), 0, stream>>>(Wk, Wq, wt);
    score_gemm<<<dim3(NFB, TOK / TB2), 512, 0, stream>>>(xh, wt, part);
    softmax_k<<<B_, 256, 0, stream>>>(part, out);
    float* vpart = part;
    const float* p_in = out + (size_t)B_ * F_;
    value_k3<<<dim3(B_, NS), 256, 0, stream>>>(x, Wv, p_in, vpart);
    value_red<<<B_ * F_ / 256, 256, 0, stream>>>(vpart, out);
}